// Round 5
// baseline (849.360 us; speedup 1.0000x reference)
//
#include <hip/hip_runtime.h>
#include <hip/hip_bf16.h>
#include <hip/hip_cooperative_groups.h>

namespace cg = cooperative_groups;

typedef __attribute__((ext_vector_type(8))) short short8;
typedef __attribute__((ext_vector_type(4))) float f32x4;
typedef unsigned short u16;
typedef unsigned int u32;

#define NBATCH 8
#define NA 1000
#define MD 64
#define GD 50
#define FD 128
#define TOTAL (NBATCH * NA)  // 8000

__device__ __forceinline__ u16 f2bf(float f) {
    u32 x = __float_as_uint(f);
    return (u16)((x + 0x7fffu + ((x >> 16) & 1u)) >> 16);  // RNE
}
__device__ __forceinline__ float bf2f(u16 u) {
    return __uint_as_float(((u32)u) << 16);
}
__device__ __forceinline__ u32 pkbf(float x, float y) {
    __hip_bfloat162 h = __float22bfloat162_rn(float2{x, y});
    return *reinterpret_cast<u32*>(&h);
}
__device__ __forceinline__ float tanh_fast(float x) {
    float e = __expf(2.0f * x);
    return 1.0f - 2.0f * __builtin_amdgcn_rcpf(e + 1.0f);
}
__device__ __forceinline__ f32x4 mfma16(short8 a, short8 b, f32x4 c) {
    return __builtin_amdgcn_mfma_f32_16x16x32_bf16(a, b, c, 0, 0, 0);
}

// ============ single cooperative kernel: pack -> init-GEMM -> CFConv+attn -> out-MLP ============
// Phase 2 body is EXACTLY round-3's k2 (proven 64 VGPR, no spill): all per-lane
// constants (b1/b2/nbrw) are loaded AT USE SITE inside the pair loop — round-4's
// hoist of these 24 values caused a 194 MB/dispatch scratch-spill catastrophe.
__global__ __launch_bounds__(256, 4) void fused(
    const float* __restrict__ feat, const float* __restrict__ rbf,
    const int* __restrict__ nl,
    const float* __restrict__ Wi, const float* __restrict__ W1,
    const float* __restrict__ b1, const float* __restrict__ W2,
    const float* __restrict__ b2, const float* __restrict__ nbrw,
    const float* __restrict__ Wo1, const float* __restrict__ bo1,
    const float* __restrict__ Wo2, const float* __restrict__ bo2,
    u16* __restrict__ initB, u16* __restrict__ W1P, u16* __restrict__ W2P,
    u16* __restrict__ WiP, u16* __restrict__ Wo1P, u16* __restrict__ Wo2P,
    float* __restrict__ outp, float* __restrict__ attnp) {
    cg::grid_group grid = cg::this_grid();
    __shared__ alignas(16) char smem[34816];
    const int tid = threadIdx.x, wid = tid >> 6, lane = tid & 63;
    const int quad = lane >> 4, col = lane & 15, rw = wid * 32;
    const int nblk = gridDim.x, blk = blockIdx.x;
    const int g0 = blk * 256 + tid, gstep = nblk * 256;
    const f32x4 zf = {0.f, 0.f, 0.f, 0.f};

    // ---------------- phase 0: pack fp32 weights into MFMA B-fragment order ----------------
    // seg = (half*2+ks)*8+nt; P[seg*512 + lane*8 + j] = bf16(W[k*FD+n]),
    // k = half*64+ks*32+(lane>>4)*8+j, n = nt*16+(lane&15). W1P: K=50 pad 64.
    for (int p = g0; p < 16 * 512; p += gstep) {
        int seg = p >> 9, l = (p >> 3) & 63, j = p & 7;
        int ks = seg >> 3, nt = seg & 7;
        int k = ks * 32 + ((l >> 4) << 3) + j;
        int n = nt * 16 + (l & 15);
        W1P[p] = (k < GD) ? f2bf(W1[k * FD + n]) : (u16)0;
    }
    for (int p = g0; p < 32 * 512; p += gstep) {
        int seg = p >> 9, l = (p >> 3) & 63, j = p & 7;
        int half = seg >> 4, ks = (seg >> 3) & 1, nt = seg & 7;
        int k = half * 64 + ks * 32 + ((l >> 4) << 3) + j;
        int n = nt * 16 + (l & 15);
        int idx = k * FD + n;
        W2P[p]  = f2bf(W2[idx]);
        WiP[p]  = f2bf(Wi[idx]);
        Wo1P[p] = f2bf(Wo1[idx]);
        Wo2P[p] = f2bf(Wo2[idx]);
    }
    __threadfence();
    grid.sync();

    // ---------------- phase 1: init = features @ W_init (500 per-wave 16-row tiles) ----------------
    for (int t = blk * 4 + wid; t < 500; t += nblk * 4) {
        const int row0 = t * 16;
        f32x4 acc[8];
#pragma unroll
        for (int nt = 0; nt < 8; ++nt) acc[nt] = zf;
#pragma unroll
        for (int half = 0; half < 2; ++half)
#pragma unroll
            for (int ks = 0; ks < 2; ++ks) {
                const int ka = half * 64 + ks * 32 + quad * 8;
                const float* src = &feat[(size_t)(row0 + col) * FD + ka];
                float4 v0 = *(const float4*)src;
                float4 v1 = *(const float4*)(src + 4);
                short8 a;
                u32* ap = (u32*)&a;
                ap[0] = pkbf(v0.x, v0.y);
                ap[1] = pkbf(v0.z, v0.w);
                ap[2] = pkbf(v1.x, v1.y);
                ap[3] = pkbf(v1.z, v1.w);
#pragma unroll
                for (int nt = 0; nt < 8; ++nt) {
                    short8 bfr = *(const short8*)&WiP[(((half * 2 + ks) * 8 + nt) << 9) + (lane << 3)];
                    acc[nt] = mfma16(a, bfr, acc[nt]);
                }
            }
#pragma unroll
        for (int nt = 0; nt < 8; ++nt)
#pragma unroll
            for (int r = 0; r < 4; ++r)
                initB[(size_t)(row0 + quad * 4 + r) * FD + nt * 16 + col] = f2bf(acc[nt][r]);
    }
    __threadfence();
    grid.sync();

    // ---------------- phase 2: fused CFConv + attention, 2 atoms / pair-task ----------------
    {
        u16* wv = (u16*)smem + wid * 4352;       // per-wave region (8704 B)
        float* logitS = (float*)smem;            // [128]    (wave0 region, post-barrier)
        float* aggS   = (float*)(smem + 1024);   // [4][128]

        for (int pair = blk; pair < 4000; pair += nblk) {
            const int b = pair / 500;
            const int n0 = (pair - b * 500) * 2;
            const int atom0 = b * NA + n0;

            // neighbor row offsets (8 ints/thread, quad-broadcast loads)
            int rowoff[2][4];
#pragma unroll
            for (int mt = 0; mt < 2; ++mt)
#pragma unroll
                for (int r = 0; r < 4; ++r)
                    rowoff[mt][r] = (b * NA + nl[atom0 * MD + rw + mt * 16 + quad * 4 + r]) * FD;

            // per-wave rbf staging: rows rw..rw+31 -> wv [32][68] bf16
            {
                const float* rsrc = rbf + (size_t)(atom0 * MD + rw) * GD;
                for (int i = lane; i < 800; i += 64) {
                    int e = 2 * i;
                    int r = e / 50, g = e - r * 50;
                    float2 v = *(const float2*)&rsrc[e];
                    *(u32*)&wv[r * 68 + g] = pkbf(v.x, v.y);
                }
                for (int i = lane; i < 448; i += 64) {  // zero K-pad cols [50,64)
                    int r = i / 14;
                    wv[r * 68 + 50 + (i - r * 14)] = 0;
                }
            }

            // layer 1: rbf @ W1
            f32x4 acc[2][8];
#pragma unroll
            for (int mt = 0; mt < 2; ++mt)
#pragma unroll
                for (int nt = 0; nt < 8; ++nt) acc[mt][nt] = zf;
#pragma unroll
            for (int ks = 0; ks < 2; ++ks) {
                const int ka = ks * 32 + quad * 8;
                short8 a0 = *(const short8*)&wv[col * 68 + ka];
                short8 a1 = *(const short8*)&wv[(16 + col) * 68 + ka];
#pragma unroll
                for (int nt = 0; nt < 8; ++nt) {
                    short8 bfr = *(const short8*)&W1P[((ks * 8 + nt) << 9) + (lane << 3)];
                    acc[0][nt] = mfma16(a0, bfr, acc[0][nt]);
                    acc[1][nt] = mfma16(a1, bfr, acc[1][nt]);
                }
            }

            // H = tanh(.+b1) -> own-wave region as [32][136] (b1 loaded at use site)
            float bias[8];
#pragma unroll
            for (int nt = 0; nt < 8; ++nt) bias[nt] = b1[nt * 16 + col];
#pragma unroll
            for (int mt = 0; mt < 2; ++mt)
#pragma unroll
                for (int nt = 0; nt < 8; ++nt)
#pragma unroll
                    for (int r = 0; r < 4; ++r) {
                        int row = mt * 16 + quad * 4 + r;
                        wv[row * 136 + nt * 16 + col] =
                            f2bf(tanh_fast(acc[mt][nt][r] + bias[nt]));
                    }

            // layer 2: H @ W2
            f32x4 acc2[2][8];
#pragma unroll
            for (int mt = 0; mt < 2; ++mt)
#pragma unroll
                for (int nt = 0; nt < 8; ++nt) acc2[mt][nt] = zf;
#pragma unroll
            for (int half = 0; half < 2; ++half)
#pragma unroll
                for (int ks = 0; ks < 2; ++ks) {
                    const int ka = half * 64 + ks * 32 + quad * 8;
                    short8 a0 = *(const short8*)&wv[col * 136 + ka];
                    short8 a1 = *(const short8*)&wv[(16 + col) * 136 + ka];
#pragma unroll
                    for (int nt = 0; nt < 8; ++nt) {
                        short8 bfr = *(const short8*)&W2P[(((half * 2 + ks) * 8 + nt) << 9) + (lane << 3)];
                        acc2[0][nt] = mfma16(a0, bfr, acc2[0][nt]);
                        acc2[1][nt] = mfma16(a1, bfr, acc2[1][nt]);
                    }
                }

            // epilogue: conv (gather at use site), logits, softmax, agg
            // b2/nbrw loaded here (use site), NOT loop-carried.
            float wv8[8];
#pragma unroll
            for (int nt = 0; nt < 8; ++nt) {
                bias[nt] = b2[nt * 16 + col];
                wv8[nt] = nbrw[nt * 16 + col];
            }
            float part[2][4] = {{0.f, 0.f, 0.f, 0.f}, {0.f, 0.f, 0.f, 0.f}};
#pragma unroll
            for (int mt = 0; mt < 2; ++mt)
#pragma unroll
                for (int nt = 0; nt < 8; ++nt)
#pragma unroll
                    for (int r = 0; r < 4; ++r) {
                        float nb = bf2f(initB[rowoff[mt][r] + nt * 16 + col]);
                        float cv = nb * (acc2[mt][nt][r] + bias[nt]);
                        acc2[mt][nt][r] = cv;  // conv stays in regs (fp32)
                        part[mt][r] += cv * wv8[nt];
                    }
#pragma unroll
            for (int d = 1; d < 16; d <<= 1)
#pragma unroll
                for (int mt = 0; mt < 2; ++mt)
#pragma unroll
                    for (int r = 0; r < 4; ++r)
                        part[mt][r] += __shfl_xor(part[mt][r], d, 64);

            __syncthreads();  // barrier 1: all waves' H reads done before aux aliases wave0 region
            if (col == 0) {
#pragma unroll
                for (int mt = 0; mt < 2; ++mt)
#pragma unroll
                    for (int r = 0; r < 4; ++r)
                        logitS[rw + mt * 16 + quad * 4 + r] = part[mt][r];
            }
            __syncthreads();  // barrier 2: logits visible

            // all-wave redundant softmax: each wave owns its atom's 64 logits
            float attw[2][4];
            {
                const int base = rw & 64;  // waves 0,1 -> atom0 ; waves 2,3 -> atom1
                float x = logitS[base + lane];
                float m = x;
#pragma unroll
                for (int d = 1; d < 64; d <<= 1) m = fmaxf(m, __shfl_xor(m, d, 64));
                float e = __expf(x - m);
                float s = e;
#pragma unroll
                for (int d = 1; d < 64; d <<= 1) s += __shfl_xor(s, d, 64);
                float a = e / s;
                if ((wid & 1) == 0)
                    attnp[(size_t)(atom0 + (wid >> 1)) * MD + lane] = a;
#pragma unroll
                for (int mt = 0; mt < 2; ++mt)
#pragma unroll
                    for (int r = 0; r < 4; ++r)
                        attw[mt][r] = __shfl(a, (rw & 32) + mt * 16 + quad * 4 + r, 64);
            }

            float aggp[8] = {0.f, 0.f, 0.f, 0.f, 0.f, 0.f, 0.f, 0.f};
#pragma unroll
            for (int mt = 0; mt < 2; ++mt)
#pragma unroll
                for (int r = 0; r < 4; ++r) {
                    float a = attw[mt][r];
#pragma unroll
                    for (int nt = 0; nt < 8; ++nt) aggp[nt] += a * acc2[mt][nt][r];
                }
#pragma unroll
            for (int d = 16; d < 64; d <<= 1)
#pragma unroll
                for (int nt = 0; nt < 8; ++nt) aggp[nt] += __shfl_xor(aggp[nt], d, 64);
            if (quad == 0) {
#pragma unroll
                for (int nt = 0; nt < 8; ++nt) aggS[wid * 128 + nt * 16 + col] = aggp[nt];
            }
            __syncthreads();  // barrier 3: partials visible
            {
                int a = tid >> 7;   // which atom
                int c = tid & 127;  // feature
                float v = aggS[(2 * a) * 128 + c] + aggS[(2 * a + 1) * 128 + c];
                outp[(size_t)(atom0 + a) * FD + c] = v;  // agg scratch in d_out rows
            }
            __syncthreads();  // barrier 4: aggS reads done before next pair's staging reuses region
        }
    }
    __threadfence();
    grid.sync();

    // ---------------- phase 3: out = tanh(agg@Wo1+bo1)@Wo2+bo2, 500 per-wave tiles ----------------
    for (int t = blk * 4 + wid; t < 500; t += nblk * 4) {
        const int row0 = t * 16;
        u16* sT = (u16*)(smem + wid * 8704);  // per-wave [16][136] u16 (4352 B of 8704)

        f32x4 acc[8];
#pragma unroll
        for (int nt = 0; nt < 8; ++nt) acc[nt] = zf;
#pragma unroll
        for (int half = 0; half < 2; ++half)
#pragma unroll
            for (int ks = 0; ks < 2; ++ks) {
                const int ka = half * 64 + ks * 32 + quad * 8;
                const float* src = &outp[(size_t)(row0 + col) * FD + ka];
                float4 v0 = *(const float4*)src;
                float4 v1 = *(const float4*)(src + 4);
                short8 a;
                u32* ap = (u32*)&a;
                ap[0] = pkbf(v0.x, v0.y);
                ap[1] = pkbf(v0.z, v0.w);
                ap[2] = pkbf(v1.x, v1.y);
                ap[3] = pkbf(v1.z, v1.w);
#pragma unroll
                for (int nt = 0; nt < 8; ++nt) {
                    short8 bfr = *(const short8*)&Wo1P[(((half * 2 + ks) * 8 + nt) << 9) + (lane << 3)];
                    acc[nt] = mfma16(a, bfr, acc[nt]);
                }
            }

#pragma unroll
        for (int nt = 0; nt < 8; ++nt) {
            float bias = bo1[nt * 16 + col];
#pragma unroll
            for (int r = 0; r < 4; ++r)
                sT[(quad * 4 + r) * 136 + nt * 16 + col] =
                    f2bf(tanh_fast(acc[nt][r] + bias));
        }
        // in-wave DS ordering: same-region write->read needs no barrier (per-wave region)

        f32x4 acc2[8];
#pragma unroll
        for (int nt = 0; nt < 8; ++nt) acc2[nt] = zf;
#pragma unroll
        for (int half = 0; half < 2; ++half)
#pragma unroll
            for (int ks = 0; ks < 2; ++ks) {
                const int ka = half * 64 + ks * 32 + quad * 8;
                short8 a0 = *(const short8*)&sT[col * 136 + ka];
#pragma unroll
                for (int nt = 0; nt < 8; ++nt) {
                    short8 bfr = *(const short8*)&Wo2P[(((half * 2 + ks) * 8 + nt) << 9) + (lane << 3)];
                    acc2[nt] = mfma16(a0, bfr, acc2[nt]);
                }
            }
#pragma unroll
        for (int nt = 0; nt < 8; ++nt) {
            float bias = bo2[nt * 16 + col];
#pragma unroll
            for (int r = 0; r < 4; ++r)
                outp[(size_t)(row0 + quad * 4 + r) * FD + nt * 16 + col] =
                    acc2[nt][r] + bias;
        }
    }
}

extern "C" void kernel_launch(void* const* d_in, const int* in_sizes, int n_in,
                              void* d_out, int out_size, void* d_ws,
                              size_t ws_size, hipStream_t stream) {
    const float* feat = (const float*)d_in[0];
    const float* rbf  = (const float*)d_in[1];
    const int*   nl   = (const int*)d_in[2];
    const float* Wi   = (const float*)d_in[3];
    const float* W1   = (const float*)d_in[4];
    const float* b1   = (const float*)d_in[5];
    const float* W2   = (const float*)d_in[6];
    const float* b2   = (const float*)d_in[7];
    const float* nbrw = (const float*)d_in[8];
    const float* Wo1  = (const float*)d_in[9];
    const float* bo1  = (const float*)d_in[10];
    const float* Wo2  = (const float*)d_in[11];
    const float* bo2  = (const float*)d_in[12];

    float* outp  = (float*)d_out;               // [8000][128] (agg scratch, then final)
    float* attnp = outp + (size_t)TOTAL * FD;   // [8000][64]

    char* ws = (char*)d_ws;                     // total use: 2,195,456 B
    u16* initB = (u16*)ws;                      // 2,048,000 B
    u16* W1P   = (u16*)(ws + 2048000);          // 16,384 B
    u16* W2P   = (u16*)(ws + 2064384);          // 32,768 B
    u16* WiP   = (u16*)(ws + 2097152);          // 32,768 B
    u16* Wo1P  = (u16*)(ws + 2129920);          // 32,768 B
    u16* Wo2P  = (u16*)(ws + 2162688);          // 32,768 B

    // co-resident grid size (expect 4 blocks/CU x 256 CU = 1024); cached
    static int nblk = 0;
    if (nblk == 0) {
        int dev = 0;
        hipGetDevice(&dev);
        hipDeviceProp_t props;
        hipGetDeviceProperties(&props, dev);
        int mbp = 0;
        hipOccupancyMaxActiveBlocksPerMultiprocessor(&mbp, (const void*)fused, 256, 0);
        if (mbp < 1) mbp = 1;
        if (mbp > 4) mbp = 4;
        nblk = props.multiProcessorCount * mbp;
        if (nblk > 4000) nblk = 4000;
        if (nblk < 64) nblk = 64;
    }

    void* args[] = {&feat, &rbf, &nl, &Wi, &W1, &b1, &W2, &b2, &nbrw,
                    &Wo1, &bo1, &Wo2, &bo2,
                    &initB, &W1P, &W2P, &WiP, &Wo1P, &Wo2P, &outp, &attnp};
    hipLaunchCooperativeKernel((const void*)fused, dim3(nblk), dim3(256), args, 0, stream);
}

// Round 7
// 268.138 us; speedup vs baseline: 3.1676x; 3.1676x over previous
//
#include <hip/hip_runtime.h>
#include <hip/hip_bf16.h>

typedef __attribute__((ext_vector_type(8))) short short8;
typedef __attribute__((ext_vector_type(4))) float f32x4;
typedef unsigned short u16;
typedef unsigned int u32;

#define NBATCH 8
#define NA 1000
#define MD 64
#define GD 50
#define FD 128
#define TOTAL (NBATCH * NA)  // 8000

__device__ __forceinline__ u16 f2bf(float f) {
    u32 x = __float_as_uint(f);
    return (u16)((x + 0x7fffu + ((x >> 16) & 1u)) >> 16);  // RNE
}
__device__ __forceinline__ float bf2f(u16 u) {
    return __uint_as_float(((u32)u) << 16);
}
__device__ __forceinline__ u32 pkbf(float x, float y) {
    __hip_bfloat162 h = __float22bfloat162_rn(float2{x, y});
    return *reinterpret_cast<u32*>(&h);
}
__device__ __forceinline__ float tanh_fast(float x) {
    float e = __expf(2.0f * x);
    return 1.0f - 2.0f * __builtin_amdgcn_rcpf(e + 1.0f);
}
__device__ __forceinline__ f32x4 mfma16(short8 a, short8 b, f32x4 c) {
    return __builtin_amdgcn_mfma_f32_16x16x32_bf16(a, b, c, 0, 0, 0);
}

// ---------------- k0: pack fp32 weights into MFMA B-fragment order ----------------
// seg = (half*2+ks)*8+nt; P[seg*512 + lane*8 + j] = bf16(W[k*FD+n]),
// k = half*64+ks*32+(lane>>4)*8+j, n = nt*16+(lane&15). W1P: K=50 pad 64.
__global__ void k0_prep(const float* __restrict__ W1, const float* __restrict__ W2,
                        const float* __restrict__ Wi, const float* __restrict__ Wo1,
                        const float* __restrict__ Wo2,
                        u16* __restrict__ W1P, u16* __restrict__ W2P,
                        u16* __restrict__ WiP, u16* __restrict__ Wo1P,
                        u16* __restrict__ Wo2P) {
    const int g0 = blockIdx.x * 256 + threadIdx.x;
    const int gstep = gridDim.x * 256;
    for (int p = g0; p < 16 * 512; p += gstep) {
        int seg = p >> 9, l = (p >> 3) & 63, j = p & 7;
        int ks = seg >> 3, nt = seg & 7;
        int k = ks * 32 + ((l >> 4) << 3) + j;
        int n = nt * 16 + (l & 15);
        W1P[p] = (k < GD) ? f2bf(W1[k * FD + n]) : (u16)0;
    }
    for (int p = g0; p < 32 * 512; p += gstep) {
        int seg = p >> 9, l = (p >> 3) & 63, j = p & 7;
        int half = seg >> 4, ks = (seg >> 3) & 1, nt = seg & 7;
        int k = half * 64 + ks * 32 + ((l >> 4) << 3) + j;
        int n = nt * 16 + (l & 15);
        int idx = k * FD + n;
        W2P[p]  = f2bf(W2[idx]);
        WiP[p]  = f2bf(Wi[idx]);
        Wo1P[p] = f2bf(Wo1[idx]);
        Wo2P[p] = f2bf(Wo2[idx]);
    }
}

// ---------------- k1: init = features @ W_init -> bf16 (TRANSPOSED-nt layout) ----------------
// initB[row*128 + col*8 + nt] = init[row][nt*16+col]  -> k2's per-(row) gather
// of 8 nt-values is ONE contiguous 16-B dwordx4.
// 500 blocks x 64 threads, 16 rows/block. No LDS, no barriers.
__global__ __launch_bounds__(64) void k1_init(const float* __restrict__ feat,
                                              const u16* __restrict__ WiP,
                                              u16* __restrict__ initB) {
    const int lane = threadIdx.x;
    const int quad = lane >> 4, col = lane & 15;
    const int row0 = blockIdx.x * 16;

    f32x4 acc[8];
    const f32x4 zf = {0.f, 0.f, 0.f, 0.f};
#pragma unroll
    for (int nt = 0; nt < 8; ++nt) acc[nt] = zf;

#pragma unroll
    for (int half = 0; half < 2; ++half)
#pragma unroll
        for (int ks = 0; ks < 2; ++ks) {
            const int ka = half * 64 + ks * 32 + quad * 8;
            const float* src = &feat[(size_t)(row0 + col) * FD + ka];
            float4 v0 = *(const float4*)src;
            float4 v1 = *(const float4*)(src + 4);
            short8 a;
            u32* ap = (u32*)&a;
            ap[0] = pkbf(v0.x, v0.y);
            ap[1] = pkbf(v0.z, v0.w);
            ap[2] = pkbf(v1.x, v1.y);
            ap[3] = pkbf(v1.z, v1.w);
#pragma unroll
            for (int nt = 0; nt < 8; ++nt) {
                short8 bfr = *(const short8*)&WiP[(((half * 2 + ks) * 8 + nt) << 9) + (lane << 3)];
                acc[nt] = mfma16(a, bfr, acc[nt]);
            }
        }
#pragma unroll
    for (int r = 0; r < 4; ++r) {
        short8 g;
#pragma unroll
        for (int nt = 0; nt < 8; ++nt) g[nt] = (short)f2bf(acc[nt][r]);
        *(short8*)&initB[(size_t)(row0 + quad * 4 + r) * FD + col * 8] = g;
    }
}

// ---------------- k2: fused CFConv + attention + out-MLP, 2 atoms / block ----------------
// Per-wave LDS region (8704 B): rbf [32][68] overlaid by H [32][136]; waves
// independent until the epilogue combine. LDS 34816 B -> 4 blocks/CU.
// Epilogue tail computes out = tanh(agg@Wo1+bo1)@Wo2+bo2 for the block's 2 atoms
// via M=2-in-16 MFMA tiles (rows 2-15 garbage, never read back) — k3 eliminated.
__global__ __launch_bounds__(256, 4) void k2_main(
    const float* __restrict__ rbf, const int* __restrict__ nl,
    const u16* __restrict__ initB,
    const u16* __restrict__ W1P, const u16* __restrict__ W2P,
    const float* __restrict__ b1, const float* __restrict__ b2,
    const float* __restrict__ nbrw,
    const u16* __restrict__ Wo1P, const u16* __restrict__ Wo2P,
    const float* __restrict__ bo1, const float* __restrict__ bo2,
    float* __restrict__ outp, float* __restrict__ attnO) {
    __shared__ alignas(16) char smem[34816];
    const int tid = threadIdx.x, wid = tid >> 6, lane = tid & 63;
    const int quad = lane >> 4, col = lane & 15, rw = wid * 32;
    const int blk = blockIdx.x;
    const int b = blk / 500;
    const int n0 = (blk - b * 500) * 2;
    const int atom0 = b * NA + n0;

    u16* wv = (u16*)smem + wid * 4352;       // per-wave region (8704 B)
    float* logitS = (float*)smem;            // [128]    bytes 0..511
    float* aggS   = (float*)(smem + 1024);   // [4][128] bytes 1024..3071
    u16* aggF = (u16*)(smem + 4096);         // [16][136] bf16, rows 0-1 valid
    u16* t1F  = (u16*)(smem + 8704 + 4352);  // [16][136] bf16, rows 0-1 valid

    // neighbor row offsets (8 ints/thread, quad-broadcast loads)
    int rowoff[2][4];
#pragma unroll
    for (int mt = 0; mt < 2; ++mt)
#pragma unroll
        for (int r = 0; r < 4; ++r)
            rowoff[mt][r] = (b * NA + nl[atom0 * MD + rw + mt * 16 + quad * 4 + r]) * FD;

    // ---- per-wave rbf staging: rows rw..rw+31 -> wv [32][68] bf16 ----
    {
        const float* rsrc = rbf + (size_t)(atom0 * MD + rw) * GD;
        for (int i = lane; i < 800; i += 64) {
            int e = 2 * i;
            int r = e / 50, g = e - r * 50;
            float2 v = *(const float2*)&rsrc[e];
            *(u32*)&wv[r * 68 + g] = pkbf(v.x, v.y);
        }
        for (int i = lane; i < 448; i += 64) {  // zero K-pad cols [50,64)
            int r = i / 14;
            wv[r * 68 + 50 + (i - r * 14)] = 0;
        }
    }

    // ---- layer 1: rbf @ W1 ----
    f32x4 acc[2][8];
    const f32x4 zf = {0.f, 0.f, 0.f, 0.f};
#pragma unroll
    for (int mt = 0; mt < 2; ++mt)
#pragma unroll
        for (int nt = 0; nt < 8; ++nt) acc[mt][nt] = zf;
#pragma unroll
    for (int ks = 0; ks < 2; ++ks) {
        const int ka = ks * 32 + quad * 8;
        short8 a0 = *(const short8*)&wv[col * 68 + ka];
        short8 a1 = *(const short8*)&wv[(16 + col) * 68 + ka];
#pragma unroll
        for (int nt = 0; nt < 8; ++nt) {
            short8 bfr = *(const short8*)&W1P[((ks * 8 + nt) << 9) + (lane << 3)];
            acc[0][nt] = mfma16(a0, bfr, acc[0][nt]);
            acc[1][nt] = mfma16(a1, bfr, acc[1][nt]);
        }
    }

    // ---- H = tanh(.+b1) -> own-wave region as [32][136] ----
    float bias[8];
#pragma unroll
    for (int nt = 0; nt < 8; ++nt) bias[nt] = b1[nt * 16 + col];
#pragma unroll
    for (int mt = 0; mt < 2; ++mt)
#pragma unroll
        for (int nt = 0; nt < 8; ++nt)
#pragma unroll
            for (int r = 0; r < 4; ++r) {
                int row = mt * 16 + quad * 4 + r;
                wv[row * 136 + nt * 16 + col] =
                    f2bf(tanh_fast(acc[mt][nt][r] + bias[nt]));
            }

    // ---- layer 2: H @ W2 ----
    f32x4 acc2[2][8];
#pragma unroll
    for (int mt = 0; mt < 2; ++mt)
#pragma unroll
        for (int nt = 0; nt < 8; ++nt) acc2[mt][nt] = zf;
#pragma unroll
    for (int half = 0; half < 2; ++half)
#pragma unroll
        for (int ks = 0; ks < 2; ++ks) {
            const int ka = half * 64 + ks * 32 + quad * 8;
            short8 a0 = *(const short8*)&wv[col * 136 + ka];
            short8 a1 = *(const short8*)&wv[(16 + col) * 136 + ka];
#pragma unroll
            for (int nt = 0; nt < 8; ++nt) {
                short8 bfr = *(const short8*)&W2P[(((half * 2 + ks) * 8 + nt) << 9) + (lane << 3)];
                acc2[0][nt] = mfma16(a0, bfr, acc2[0][nt]);
                acc2[1][nt] = mfma16(a1, bfr, acc2[1][nt]);
            }
        }

    // ---- epilogue: conv (vector gather: ONE dwordx4 per neighbor row), logits ----
    float wv8[8];
#pragma unroll
    for (int nt = 0; nt < 8; ++nt) {
        bias[nt] = b2[nt * 16 + col];
        wv8[nt] = nbrw[nt * 16 + col];
    }
    float part[2][4] = {{0.f, 0.f, 0.f, 0.f}, {0.f, 0.f, 0.f, 0.f}};
#pragma unroll
    for (int mt = 0; mt < 2; ++mt)
#pragma unroll
        for (int r = 0; r < 4; ++r) {
            short8 g = *(const short8*)&initB[rowoff[mt][r] + col * 8];
#pragma unroll
            for (int nt = 0; nt < 8; ++nt) {
                float nb = bf2f((u16)g[nt]);
                float cv = nb * (acc2[mt][nt][r] + bias[nt]);
                acc2[mt][nt][r] = cv;  // conv stays in regs (fp32)
                part[mt][r] += cv * wv8[nt];
            }
        }
#pragma unroll
    for (int d = 1; d < 16; d <<= 1)
#pragma unroll
        for (int mt = 0; mt < 2; ++mt)
#pragma unroll
            for (int r = 0; r < 4; ++r)
                part[mt][r] += __shfl_xor(part[mt][r], d, 64);

    __syncthreads();  // barrier 1: all waves' H reads done before aux aliases regions
    if (col == 0) {
#pragma unroll
        for (int mt = 0; mt < 2; ++mt)
#pragma unroll
            for (int r = 0; r < 4; ++r)
                logitS[rw + mt * 16 + quad * 4 + r] = part[mt][r];
    }
    __syncthreads();  // barrier 2: logits visible

    // all-wave redundant softmax
    float attw[2][4];
    {
        const int base = rw & 64;  // waves 0,1 -> atom0 ; waves 2,3 -> atom1
        float x = logitS[base + lane];
        float m = x;
#pragma unroll
        for (int d = 1; d < 64; d <<= 1) m = fmaxf(m, __shfl_xor(m, d, 64));
        float e = __expf(x - m);
        float s = e;
#pragma unroll
        for (int d = 1; d < 64; d <<= 1) s += __shfl_xor(s, d, 64);
        float a = e / s;
        if ((wid & 1) == 0)
            attnO[(size_t)(atom0 + (wid >> 1)) * MD + lane] = a;
#pragma unroll
        for (int mt = 0; mt < 2; ++mt)
#pragma unroll
            for (int r = 0; r < 4; ++r)
                attw[mt][r] = __shfl(a, (rw & 32) + mt * 16 + quad * 4 + r, 64);
    }

    float aggp[8] = {0.f, 0.f, 0.f, 0.f, 0.f, 0.f, 0.f, 0.f};
#pragma unroll
    for (int mt = 0; mt < 2; ++mt)
#pragma unroll
        for (int r = 0; r < 4; ++r) {
            float a = attw[mt][r];
#pragma unroll
            for (int nt = 0; nt < 8; ++nt) aggp[nt] += a * acc2[mt][nt][r];
        }
#pragma unroll
    for (int d = 16; d < 64; d <<= 1)
#pragma unroll
        for (int nt = 0; nt < 8; ++nt) aggp[nt] += __shfl_xor(aggp[nt], d, 64);
    if (quad == 0) {
#pragma unroll
        for (int nt = 0; nt < 8; ++nt) aggS[wid * 128 + nt * 16 + col] = aggp[nt];
    }
    __syncthreads();  // barrier 3: partials visible

    // ---- fused out-MLP: out = tanh(agg@Wo1+bo1)@Wo2+bo2 for the block's 2 atoms ----
    {
        int a = tid >> 7, c = tid & 127;
        float v = aggS[(2 * a) * 128 + c] + aggS[(2 * a + 1) * 128 + c];
        aggF[a * 136 + c] = f2bf(v);  // A-frag rows 0-1; rows 2-15 garbage (unused)
    }
    __syncthreads();  // barrier 4: aggF visible

    f32x4 o0 = zf, o1v = zf;  // this wave's two nt-tiles (nt = 2*wid, 2*wid+1)
#pragma unroll
    for (int half = 0; half < 2; ++half)
#pragma unroll
        for (int ks = 0; ks < 2; ++ks) {
            const int ka = half * 64 + ks * 32 + quad * 8;
            short8 a0 = *(const short8*)&aggF[col * 136 + ka];
            short8 bf0 = *(const short8*)&Wo1P[(((half * 2 + ks) * 8 + 2 * wid) << 9) + (lane << 3)];
            short8 bf1 = *(const short8*)&Wo1P[(((half * 2 + ks) * 8 + 2 * wid + 1) << 9) + (lane << 3)];
            o0 = mfma16(a0, bf0, o0);
            o1v = mfma16(a0, bf1, o1v);
        }
    if (quad == 0) {
        float bb0 = bo1[(2 * wid) * 16 + col];
        float bb1 = bo1[(2 * wid + 1) * 16 + col];
#pragma unroll
        for (int r = 0; r < 2; ++r) {
            t1F[r * 136 + (2 * wid) * 16 + col] = f2bf(tanh_fast(o0[r] + bb0));
            t1F[r * 136 + (2 * wid + 1) * 16 + col] = f2bf(tanh_fast(o1v[r] + bb1));
        }
    }
    __syncthreads();  // barrier 5: t1F visible

    o0 = zf; o1v = zf;
#pragma unroll
    for (int half = 0; half < 2; ++half)
#pragma unroll
        for (int ks = 0; ks < 2; ++ks) {
            const int ka = half * 64 + ks * 32 + quad * 8;
            short8 a0 = *(const short8*)&t1F[col * 136 + ka];
            short8 bf0 = *(const short8*)&Wo2P[(((half * 2 + ks) * 8 + 2 * wid) << 9) + (lane << 3)];
            short8 bf1 = *(const short8*)&Wo2P[(((half * 2 + ks) * 8 + 2 * wid + 1) << 9) + (lane << 3)];
            o0 = mfma16(a0, bf0, o0);
            o1v = mfma16(a0, bf1, o1v);
        }
    if (quad == 0) {
        float bb0 = bo2[(2 * wid) * 16 + col];
        float bb1 = bo2[(2 * wid + 1) * 16 + col];
#pragma unroll
        for (int r = 0; r < 2; ++r) {
            outp[(size_t)(atom0 + r) * FD + (2 * wid) * 16 + col] = o0[r] + bb0;
            outp[(size_t)(atom0 + r) * FD + (2 * wid + 1) * 16 + col] = o1v[r] + bb1;
        }
    }
}

extern "C" void kernel_launch(void* const* d_in, const int* in_sizes, int n_in,
                              void* d_out, int out_size, void* d_ws,
                              size_t ws_size, hipStream_t stream) {
    const float* feat = (const float*)d_in[0];
    const float* rbf  = (const float*)d_in[1];
    const int*   nl   = (const int*)d_in[2];
    const float* Wi   = (const float*)d_in[3];
    const float* W1   = (const float*)d_in[4];
    const float* b1   = (const float*)d_in[5];
    const float* W2   = (const float*)d_in[6];
    const float* b2   = (const float*)d_in[7];
    const float* nbrw = (const float*)d_in[8];
    const float* Wo1  = (const float*)d_in[9];
    const float* bo1  = (const float*)d_in[10];
    const float* Wo2  = (const float*)d_in[11];
    const float* bo2  = (const float*)d_in[12];

    float* outp  = (float*)d_out;               // [8000][128] final out
    float* attnp = outp + (size_t)TOTAL * FD;   // [8000][64]

    char* ws = (char*)d_ws;                     // total use: 2,195,456 B
    u16* initB = (u16*)ws;                      // 2,048,000 B
    u16* W1P   = (u16*)(ws + 2048000);          // 16,384 B
    u16* W2P   = (u16*)(ws + 2064384);          // 32,768 B
    u16* WiP   = (u16*)(ws + 2097152);          // 32,768 B
    u16* Wo1P  = (u16*)(ws + 2129920);          // 32,768 B
    u16* Wo2P  = (u16*)(ws + 2162688);          // 32,768 B

    hipLaunchKernelGGL(k0_prep, dim3(40), dim3(256), 0, stream,
                       W1, W2, Wi, Wo1, Wo2, W1P, W2P, WiP, Wo1P, Wo2P);
    hipLaunchKernelGGL(k1_init, dim3(500), dim3(64), 0, stream, feat, WiP, initB);
    hipLaunchKernelGGL(k2_main, dim3(4000), dim3(256), 0, stream,
                       rbf, nl, initB, W1P, W2P, b1, b2, nbrw,
                       Wo1P, Wo2P, bo1, bo2, outp, attnp);
}

// Round 8
// 259.663 us; speedup vs baseline: 3.2710x; 1.0326x over previous
//
#include <hip/hip_runtime.h>
#include <hip/hip_bf16.h>

typedef __attribute__((ext_vector_type(8))) short short8;
typedef __attribute__((ext_vector_type(4))) float f32x4;
typedef unsigned short u16;
typedef unsigned int u32;

#define NBATCH 8
#define NA 1000
#define MD 64
#define GD 50
#define FD 128
#define TOTAL (NBATCH * NA)  // 8000

__device__ __forceinline__ u16 f2bf(float f) {
    u32 x = __float_as_uint(f);
    return (u16)((x + 0x7fffu + ((x >> 16) & 1u)) >> 16);  // RNE
}
__device__ __forceinline__ float bf2f(u16 u) {
    return __uint_as_float(((u32)u) << 16);
}
__device__ __forceinline__ u32 pkbf(float x, float y) {
    __hip_bfloat162 h = __float22bfloat162_rn(float2{x, y});
    return *reinterpret_cast<u32*>(&h);
}
__device__ __forceinline__ float tanh_fast(float x) {
    float e = __expf(2.0f * x);
    return 1.0f - 2.0f * __builtin_amdgcn_rcpf(e + 1.0f);
}
__device__ __forceinline__ f32x4 mfma16(short8 a, short8 b, f32x4 c) {
    return __builtin_amdgcn_mfma_f32_16x16x32_bf16(a, b, c, 0, 0, 0);
}

// ---------------- k0: pack fp32 weights into MFMA B-fragment order ----------------
// seg = (half*2+ks)*8+nt; P[seg*512 + lane*8 + j] = bf16(W[k*FD+n]),
// kstor = half*64+ks*32+(lane>>4)*8+j, n = nt*16+(lane&15). W1P: K=50 pad 64.
// W2P/Wo2P use K-PERMUTED rows: slot kstor holds feature f = (kstor>>3)|((kstor&7)<<4),
// matching the producer-packed H/t1 LDS layout [row][col*8+nt] (GEMM invariant
// under joint K-permutation). WiP/Wo1P natural (their A-operands are natural).
__global__ void k0_prep(const float* __restrict__ W1, const float* __restrict__ W2,
                        const float* __restrict__ Wi, const float* __restrict__ Wo1,
                        const float* __restrict__ Wo2,
                        u16* __restrict__ W1P, u16* __restrict__ W2P,
                        u16* __restrict__ WiP, u16* __restrict__ Wo1P,
                        u16* __restrict__ Wo2P) {
    const int g0 = blockIdx.x * 256 + threadIdx.x;
    const int gstep = gridDim.x * 256;
    for (int p = g0; p < 16 * 512; p += gstep) {
        int seg = p >> 9, l = (p >> 3) & 63, j = p & 7;
        int ks = seg >> 3, nt = seg & 7;
        int k = ks * 32 + ((l >> 4) << 3) + j;
        int n = nt * 16 + (l & 15);
        W1P[p] = (k < GD) ? f2bf(W1[k * FD + n]) : (u16)0;
    }
    for (int p = g0; p < 32 * 512; p += gstep) {
        int seg = p >> 9, l = (p >> 3) & 63, j = p & 7;
        int half = seg >> 4, ks = (seg >> 3) & 1, nt = seg & 7;
        int kstor = half * 64 + ks * 32 + ((l >> 4) << 3) + j;
        int n = nt * 16 + (l & 15);
        WiP[p]  = f2bf(Wi[kstor * FD + n]);
        Wo1P[p] = f2bf(Wo1[kstor * FD + n]);
        int kperm = (kstor >> 3) | ((kstor & 7) << 4);
        W2P[p]  = f2bf(W2[kperm * FD + n]);
        Wo2P[p] = f2bf(Wo2[kperm * FD + n]);
    }
}

// ---------------- k1: init = features @ W_init -> bf16 (TRANSPOSED-nt layout) ----------------
// initB[row*128 + col*8 + nt] = init[row][nt*16+col]  -> k2's per-row gather of
// 8 nt-values is ONE contiguous 16-B dwordx4. 500 blocks x 64 threads.
__global__ __launch_bounds__(64) void k1_init(const float* __restrict__ feat,
                                              const u16* __restrict__ WiP,
                                              u16* __restrict__ initB) {
    const int lane = threadIdx.x;
    const int quad = lane >> 4, col = lane & 15;
    const int row0 = blockIdx.x * 16;

    f32x4 acc[8];
    const f32x4 zf = {0.f, 0.f, 0.f, 0.f};
#pragma unroll
    for (int nt = 0; nt < 8; ++nt) acc[nt] = zf;

#pragma unroll
    for (int half = 0; half < 2; ++half)
#pragma unroll
        for (int ks = 0; ks < 2; ++ks) {
            const int ka = half * 64 + ks * 32 + quad * 8;
            const float* src = &feat[(size_t)(row0 + col) * FD + ka];
            float4 v0 = *(const float4*)src;
            float4 v1 = *(const float4*)(src + 4);
            short8 a;
            u32* ap = (u32*)&a;
            ap[0] = pkbf(v0.x, v0.y);
            ap[1] = pkbf(v0.z, v0.w);
            ap[2] = pkbf(v1.x, v1.y);
            ap[3] = pkbf(v1.z, v1.w);
#pragma unroll
            for (int nt = 0; nt < 8; ++nt) {
                short8 bfr = *(const short8*)&WiP[(((half * 2 + ks) * 8 + nt) << 9) + (lane << 3)];
                acc[nt] = mfma16(a, bfr, acc[nt]);
            }
        }
#pragma unroll
    for (int r = 0; r < 4; ++r) {
        short8 g;
        u32* gp = (u32*)&g;
        gp[0] = pkbf(acc[0][r], acc[1][r]);
        gp[1] = pkbf(acc[2][r], acc[3][r]);
        gp[2] = pkbf(acc[4][r], acc[5][r]);
        gp[3] = pkbf(acc[6][r], acc[7][r]);
        *(short8*)&initB[(size_t)(row0 + quad * 4 + r) * FD + col * 8] = g;
    }
}

// ---------------- k2: fused CFConv + attention, 2 atoms / block ----------------
// Per-wave LDS region (8704 B): rbf [32][68] overlaid by H [32][136] (PACKED:
// H[row][col*8+nt], one ds_write_b128 per (mt,r), W2P K-permuted to match).
// b1/b2 folded into MFMA C-init. LDS 34816 B -> 4 blocks/CU. 3 barriers.
__global__ __launch_bounds__(256, 4) void k2_main(
    const float* __restrict__ rbf, const int* __restrict__ nl,
    const u16* __restrict__ initB,
    const u16* __restrict__ W1P, const u16* __restrict__ W2P,
    const float* __restrict__ b1, const float* __restrict__ b2,
    const float* __restrict__ nbrw,
    float* __restrict__ aggOut, float* __restrict__ attnO) {
    __shared__ alignas(16) char smem[34816];
    const int tid = threadIdx.x, wid = tid >> 6, lane = tid & 63;
    const int quad = lane >> 4, col = lane & 15, rw = wid * 32;
    const int blk = blockIdx.x;
    const int b = blk / 500;
    const int n0 = (blk - b * 500) * 2;
    const int atom0 = b * NA + n0;

    u16* wv = (u16*)smem + wid * 4352;       // per-wave region (8704 B)
    float* logitS = (float*)smem;            // [128]    bytes 0..511
    float* aggS   = (float*)(smem + 1024);   // [4][128] bytes 1024..3071

    // neighbor row offsets (8 ints/thread, quad-broadcast loads)
    int rowoff[2][4];
#pragma unroll
    for (int mt = 0; mt < 2; ++mt)
#pragma unroll
        for (int r = 0; r < 4; ++r)
            rowoff[mt][r] = (b * NA + nl[atom0 * MD + rw + mt * 16 + quad * 4 + r]) * FD;

    // ---- per-wave rbf staging: rows rw..rw+31 -> wv [32][68] bf16 ----
    {
        const float* rsrc = rbf + (size_t)(atom0 * MD + rw) * GD;
        for (int i = lane; i < 800; i += 64) {
            int e = 2 * i;
            int r = e / 50, g = e - r * 50;
            float2 v = *(const float2*)&rsrc[e];
            *(u32*)&wv[r * 68 + g] = pkbf(v.x, v.y);
        }
        for (int i = lane; i < 448; i += 64) {  // zero K-pad cols [50,64)
            int r = i / 14;
            wv[r * 68 + 50 + (i - r * 14)] = 0;
        }
    }

    // ---- layer 1: rbf @ W1, C-init = b1 broadcast (bias folded into MFMA) ----
    f32x4 acc[2][8];
#pragma unroll
    for (int nt = 0; nt < 8; ++nt) {
        float bb = b1[nt * 16 + col];
        f32x4 c = {bb, bb, bb, bb};
        acc[0][nt] = c;
        acc[1][nt] = c;
    }
#pragma unroll
    for (int ks = 0; ks < 2; ++ks) {
        const int ka = ks * 32 + quad * 8;
        short8 a0 = *(const short8*)&wv[col * 68 + ka];
        short8 a1 = *(const short8*)&wv[(16 + col) * 68 + ka];
#pragma unroll
        for (int nt = 0; nt < 8; ++nt) {
            short8 bfr = *(const short8*)&W1P[((ks * 8 + nt) << 9) + (lane << 3)];
            acc[0][nt] = mfma16(a0, bfr, acc[0][nt]);
            acc[1][nt] = mfma16(a1, bfr, acc[1][nt]);
        }
    }

    // ---- H = tanh(acc) -> own-wave region PACKED [32 rows][col*8+nt] ----
    // per (mt,r): 8 tanh -> 4 cvt_pk -> ONE ds_write_b128 (was 64 b16 writes)
#pragma unroll
    for (int mt = 0; mt < 2; ++mt)
#pragma unroll
        for (int r = 0; r < 4; ++r) {
            short8 h;
            u32* hp = (u32*)&h;
            hp[0] = pkbf(tanh_fast(acc[mt][0][r]), tanh_fast(acc[mt][1][r]));
            hp[1] = pkbf(tanh_fast(acc[mt][2][r]), tanh_fast(acc[mt][3][r]));
            hp[2] = pkbf(tanh_fast(acc[mt][4][r]), tanh_fast(acc[mt][5][r]));
            hp[3] = pkbf(tanh_fast(acc[mt][6][r]), tanh_fast(acc[mt][7][r]));
            *(short8*)&wv[(mt * 16 + quad * 4 + r) * 136 + col * 8] = h;
        }

    // ---- layer 2: H @ W2 (K-permuted storage order), C-init = b2 broadcast ----
    f32x4 acc2[2][8];
#pragma unroll
    for (int nt = 0; nt < 8; ++nt) {
        float bb = b2[nt * 16 + col];
        f32x4 c = {bb, bb, bb, bb};
        acc2[0][nt] = c;
        acc2[1][nt] = c;
    }
#pragma unroll
    for (int half = 0; half < 2; ++half)
#pragma unroll
        for (int ks = 0; ks < 2; ++ks) {
            const int ka = half * 64 + ks * 32 + quad * 8;
            short8 a0 = *(const short8*)&wv[col * 136 + ka];
            short8 a1 = *(const short8*)&wv[(16 + col) * 136 + ka];
#pragma unroll
            for (int nt = 0; nt < 8; ++nt) {
                short8 bfr = *(const short8*)&W2P[(((half * 2 + ks) * 8 + nt) << 9) + (lane << 3)];
                acc2[0][nt] = mfma16(a0, bfr, acc2[0][nt]);
                acc2[1][nt] = mfma16(a1, bfr, acc2[1][nt]);
            }
        }

    // ---- epilogue: conv (vector gather, acc2 already = filt), logits ----
    float wv8[8];
#pragma unroll
    for (int nt = 0; nt < 8; ++nt) wv8[nt] = nbrw[nt * 16 + col];
    float part[2][4] = {{0.f, 0.f, 0.f, 0.f}, {0.f, 0.f, 0.f, 0.f}};
#pragma unroll
    for (int mt = 0; mt < 2; ++mt)
#pragma unroll
        for (int r = 0; r < 4; ++r) {
            short8 g = *(const short8*)&initB[rowoff[mt][r] + col * 8];
#pragma unroll
            for (int nt = 0; nt < 8; ++nt) {
                float nb = bf2f((u16)g[nt]);
                float cv = nb * acc2[mt][nt][r];
                acc2[mt][nt][r] = cv;  // conv stays in regs (fp32)
                part[mt][r] += cv * wv8[nt];
            }
        }
#pragma unroll
    for (int d = 1; d < 16; d <<= 1)
#pragma unroll
        for (int mt = 0; mt < 2; ++mt)
#pragma unroll
            for (int r = 0; r < 4; ++r)
                part[mt][r] += __shfl_xor(part[mt][r], d, 64);

    __syncthreads();  // barrier 1: all waves' H reads done before aux aliases wave0 region
    if (col == 0) {
#pragma unroll
        for (int mt = 0; mt < 2; ++mt)
#pragma unroll
            for (int r = 0; r < 4; ++r)
                logitS[rw + mt * 16 + quad * 4 + r] = part[mt][r];
    }
    __syncthreads();  // barrier 2: logits visible

    // all-wave redundant softmax: each wave owns its atom's 64 logits
    float attw[2][4];
    {
        const int base = rw & 64;  // waves 0,1 -> atom0 ; waves 2,3 -> atom1
        float x = logitS[base + lane];
        float m = x;
#pragma unroll
        for (int d = 1; d < 64; d <<= 1) m = fmaxf(m, __shfl_xor(m, d, 64));
        float e = __expf(x - m);
        float s = e;
#pragma unroll
        for (int d = 1; d < 64; d <<= 1) s += __shfl_xor(s, d, 64);
        float a = e / s;
        if ((wid & 1) == 0)
            attnO[(size_t)(atom0 + (wid >> 1)) * MD + lane] = a;
#pragma unroll
        for (int mt = 0; mt < 2; ++mt)
#pragma unroll
            for (int r = 0; r < 4; ++r)
                attw[mt][r] = __shfl(a, (rw & 32) + mt * 16 + quad * 4 + r, 64);
    }

    float aggp[8] = {0.f, 0.f, 0.f, 0.f, 0.f, 0.f, 0.f, 0.f};
#pragma unroll
    for (int mt = 0; mt < 2; ++mt)
#pragma unroll
        for (int r = 0; r < 4; ++r) {
            float a = attw[mt][r];
#pragma unroll
            for (int nt = 0; nt < 8; ++nt) aggp[nt] += a * acc2[mt][nt][r];
        }
#pragma unroll
    for (int d = 16; d < 64; d <<= 1)
#pragma unroll
        for (int nt = 0; nt < 8; ++nt) aggp[nt] += __shfl_xor(aggp[nt], d, 64);
    if (quad == 0) {
#pragma unroll
        for (int nt = 0; nt < 8; ++nt) aggS[wid * 128 + nt * 16 + col] = aggp[nt];
    }
    __syncthreads();  // barrier 3: partials visible
    {
        int a = tid >> 7;   // which atom
        int c = tid & 127;  // feature
        float v = aggS[(2 * a) * 128 + c] + aggS[(2 * a + 1) * 128 + c];
        aggOut[(size_t)(atom0 + a) * FD + c] = v;  // agg scratch in d_out rows
    }
}

// ---------------- k3: out = tanh(agg@Wo1+bo1)@Wo2+bo2, IN PLACE on d_out rows ----------------
// 500 blocks x 64 threads, 16 rows/block. t1 PACKED [row][col*8+nt] with
// Wo2P K-permuted; bo1/bo2 folded into MFMA C-init. Single 1-wave barrier.
__global__ __launch_bounds__(64) void k3_out(
    float* __restrict__ outp, const u16* __restrict__ Wo1P,
    const u16* __restrict__ Wo2P, const float* __restrict__ bo1,
    const float* __restrict__ bo2) {
    __shared__ alignas(16) u16 sT[16 * 136];
    const int lane = threadIdx.x;
    const int quad = lane >> 4, col = lane & 15;
    const int row0 = blockIdx.x * 16;

    f32x4 acc[8];
#pragma unroll
    for (int nt = 0; nt < 8; ++nt) {
        float bb = bo1[nt * 16 + col];
        f32x4 c = {bb, bb, bb, bb};
        acc[nt] = c;
    }
#pragma unroll
    for (int half = 0; half < 2; ++half)
#pragma unroll
        for (int ks = 0; ks < 2; ++ks) {
            const int ka = half * 64 + ks * 32 + quad * 8;
            const float* src = &outp[(size_t)(row0 + col) * FD + ka];
            float4 v0 = *(const float4*)src;
            float4 v1 = *(const float4*)(src + 4);
            short8 a;
            u32* ap = (u32*)&a;
            ap[0] = pkbf(v0.x, v0.y);
            ap[1] = pkbf(v0.z, v0.w);
            ap[2] = pkbf(v1.x, v1.y);
            ap[3] = pkbf(v1.z, v1.w);
#pragma unroll
            for (int nt = 0; nt < 8; ++nt) {
                short8 bfr = *(const short8*)&Wo1P[(((half * 2 + ks) * 8 + nt) << 9) + (lane << 3)];
                acc[nt] = mfma16(a, bfr, acc[nt]);
            }
        }

#pragma unroll
    for (int r = 0; r < 4; ++r) {
        short8 h;
        u32* hp = (u32*)&h;
        hp[0] = pkbf(tanh_fast(acc[0][r]), tanh_fast(acc[1][r]));
        hp[1] = pkbf(tanh_fast(acc[2][r]), tanh_fast(acc[3][r]));
        hp[2] = pkbf(tanh_fast(acc[4][r]), tanh_fast(acc[5][r]));
        hp[3] = pkbf(tanh_fast(acc[6][r]), tanh_fast(acc[7][r]));
        *(short8*)&sT[(quad * 4 + r) * 136 + col * 8] = h;
    }
    __syncthreads();  // single-wave block: cheap; guarantees t1 write->read order

    f32x4 acc2[8];
#pragma unroll
    for (int nt = 0; nt < 8; ++nt) {
        float bb = bo2[nt * 16 + col];
        f32x4 c = {bb, bb, bb, bb};
        acc2[nt] = c;
    }
#pragma unroll
    for (int half = 0; half < 2; ++half)
#pragma unroll
        for (int ks = 0; ks < 2; ++ks) {
            const int ka = half * 64 + ks * 32 + quad * 8;
            short8 a0 = *(const short8*)&sT[col * 136 + ka];
#pragma unroll
            for (int nt = 0; nt < 8; ++nt) {
                short8 bfr = *(const short8*)&Wo2P[(((half * 2 + ks) * 8 + nt) << 9) + (lane << 3)];
                acc2[nt] = mfma16(a0, bfr, acc2[nt]);
            }
        }
#pragma unroll
    for (int nt = 0; nt < 8; ++nt)
#pragma unroll
        for (int r = 0; r < 4; ++r)
            outp[(size_t)(row0 + quad * 4 + r) * FD + nt * 16 + col] = acc2[nt][r];
}

extern "C" void kernel_launch(void* const* d_in, const int* in_sizes, int n_in,
                              void* d_out, int out_size, void* d_ws,
                              size_t ws_size, hipStream_t stream) {
    const float* feat = (const float*)d_in[0];
    const float* rbf  = (const float*)d_in[1];
    const int*   nl   = (const int*)d_in[2];
    const float* Wi   = (const float*)d_in[3];
    const float* W1   = (const float*)d_in[4];
    const float* b1   = (const float*)d_in[5];
    const float* W2   = (const float*)d_in[6];
    const float* b2   = (const float*)d_in[7];
    const float* nbrw = (const float*)d_in[8];
    const float* Wo1  = (const float*)d_in[9];
    const float* bo1  = (const float*)d_in[10];
    const float* Wo2  = (const float*)d_in[11];
    const float* bo2  = (const float*)d_in[12];

    float* outp  = (float*)d_out;               // [8000][128] (agg scratch, then final)
    float* attnp = outp + (size_t)TOTAL * FD;   // [8000][64]

    char* ws = (char*)d_ws;                     // total use: 2,195,456 B
    u16* initB = (u16*)ws;                      // 2,048,000 B
    u16* W1P   = (u16*)(ws + 2048000);          // 16,384 B
    u16* W2P   = (u16*)(ws + 2064384);          // 32,768 B
    u16* WiP   = (u16*)(ws + 2097152);          // 32,768 B
    u16* Wo1P  = (u16*)(ws + 2129920);          // 32,768 B
    u16* Wo2P  = (u16*)(ws + 2162688);          // 32,768 B

    hipLaunchKernelGGL(k0_prep, dim3(40), dim3(256), 0, stream,
                       W1, W2, Wi, Wo1, Wo2, W1P, W2P, WiP, Wo1P, Wo2P);
    hipLaunchKernelGGL(k1_init, dim3(500), dim3(64), 0, stream, feat, WiP, initB);
    hipLaunchKernelGGL(k2_main, dim3(4000), dim3(256), 0, stream,
                       rbf, nl, initB, W1P, W2P, b1, b2, nbrw, outp, attnp);
    hipLaunchKernelGGL(k3_out, dim3(500), dim3(64), 0, stream,
                       outp, Wo1P, Wo2P, bo1, bo2);
}

// Round 9
// 251.291 us; speedup vs baseline: 3.3800x; 1.0333x over previous
//
#include <hip/hip_runtime.h>
#include <hip/hip_bf16.h>

typedef __attribute__((ext_vector_type(8))) short short8;
typedef __attribute__((ext_vector_type(4))) float f32x4;
typedef unsigned short u16;
typedef unsigned int u32;

#define NBATCH 8
#define NA 1000
#define MD 64
#define GD 50
#define FD 128
#define TOTAL (NBATCH * NA)  // 8000

__device__ __forceinline__ u16 f2bf(float f) {
    u32 x = __float_as_uint(f);
    return (u16)((x + 0x7fffu + ((x >> 16) & 1u)) >> 16);  // RNE
}
__device__ __forceinline__ float bf2f(u16 u) {
    return __uint_as_float(((u32)u) << 16);
}
__device__ __forceinline__ u32 pkbf(float x, float y) {
    __hip_bfloat162 h = __float22bfloat162_rn(float2{x, y});
    return *reinterpret_cast<u32*>(&h);
}
__device__ __forceinline__ float tanh_fast(float x) {
    float e = __expf(2.0f * x);
    return 1.0f - 2.0f * __builtin_amdgcn_rcpf(e + 1.0f);
}
__device__ __forceinline__ f32x4 mfma16(short8 a, short8 b, f32x4 c) {
    return __builtin_amdgcn_mfma_f32_16x16x32_bf16(a, b, c, 0, 0, 0);
}

// ---------------- k0: pack fp32 weights into MFMA B-fragment order ----------------
// seg = (half*2+ks)*8+nt; P[seg*512 + lane*8 + j] = bf16(W[k*FD+n]),
// kstor = half*64+ks*32+(lane>>4)*8+j, n = nt*16+(lane&15). W1P: K=50 pad 64.
// W2P/Wo2P use K-PERMUTED rows: slot kstor holds feature f = (kstor>>3)|((kstor&7)<<4),
// matching the producer-packed H/t1 LDS layout [row][col*8+nt] (GEMM invariant
// under joint K-permutation). WiP/Wo1P natural.
__global__ void k0_prep(const float* __restrict__ W1, const float* __restrict__ W2,
                        const float* __restrict__ Wi, const float* __restrict__ Wo1,
                        const float* __restrict__ Wo2,
                        u16* __restrict__ W1P, u16* __restrict__ W2P,
                        u16* __restrict__ WiP, u16* __restrict__ Wo1P,
                        u16* __restrict__ Wo2P) {
    const int g0 = blockIdx.x * 256 + threadIdx.x;
    const int gstep = gridDim.x * 256;
    for (int p = g0; p < 16 * 512; p += gstep) {
        int seg = p >> 9, l = (p >> 3) & 63, j = p & 7;
        int ks = seg >> 3, nt = seg & 7;
        int k = ks * 32 + ((l >> 4) << 3) + j;
        int n = nt * 16 + (l & 15);
        W1P[p] = (k < GD) ? f2bf(W1[k * FD + n]) : (u16)0;
    }
    for (int p = g0; p < 32 * 512; p += gstep) {
        int seg = p >> 9, l = (p >> 3) & 63, j = p & 7;
        int half = seg >> 4, ks = (seg >> 3) & 1, nt = seg & 7;
        int kstor = half * 64 + ks * 32 + ((l >> 4) << 3) + j;
        int n = nt * 16 + (l & 15);
        WiP[p]  = f2bf(Wi[kstor * FD + n]);
        Wo1P[p] = f2bf(Wo1[kstor * FD + n]);
        int kperm = (kstor >> 3) | ((kstor & 7) << 4);
        W2P[p]  = f2bf(W2[kperm * FD + n]);
        Wo2P[p] = f2bf(Wo2[kperm * FD + n]);
    }
}

// ---------------- k1: init = features @ W_init -> bf16 (TRANSPOSED-nt layout) ----------------
// initB[row*128 + col*8 + nt] = init[row][nt*16+col]  -> k2's per-row gather of
// 8 nt-values is ONE contiguous 16-B dwordx4. 500 blocks x 64 threads.
__global__ __launch_bounds__(64) void k1_init(const float* __restrict__ feat,
                                              const u16* __restrict__ WiP,
                                              u16* __restrict__ initB) {
    const int lane = threadIdx.x;
    const int quad = lane >> 4, col = lane & 15;
    const int row0 = blockIdx.x * 16;

    f32x4 acc[8];
    const f32x4 zf = {0.f, 0.f, 0.f, 0.f};
#pragma unroll
    for (int nt = 0; nt < 8; ++nt) acc[nt] = zf;

#pragma unroll
    for (int half = 0; half < 2; ++half)
#pragma unroll
        for (int ks = 0; ks < 2; ++ks) {
            const int ka = half * 64 + ks * 32 + quad * 8;
            const float* src = &feat[(size_t)(row0 + col) * FD + ka];
            float4 v0 = *(const float4*)src;
            float4 v1 = *(const float4*)(src + 4);
            short8 a;
            u32* ap = (u32*)&a;
            ap[0] = pkbf(v0.x, v0.y);
            ap[1] = pkbf(v0.z, v0.w);
            ap[2] = pkbf(v1.x, v1.y);
            ap[3] = pkbf(v1.z, v1.w);
#pragma unroll
            for (int nt = 0; nt < 8; ++nt) {
                short8 bfr = *(const short8*)&WiP[(((half * 2 + ks) * 8 + nt) << 9) + (lane << 3)];
                acc[nt] = mfma16(a, bfr, acc[nt]);
            }
        }
#pragma unroll
    for (int r = 0; r < 4; ++r) {
        short8 g;
        u32* gp = (u32*)&g;
        gp[0] = pkbf(acc[0][r], acc[1][r]);
        gp[1] = pkbf(acc[2][r], acc[3][r]);
        gp[2] = pkbf(acc[4][r], acc[5][r]);
        gp[3] = pkbf(acc[6][r], acc[7][r]);
        *(short8*)&initB[(size_t)(row0 + quad * 4 + r) * FD + col * 8] = g;
    }
}

// ---------------- k2: fused CFConv + attention, 1 ATOM / block (8000 blocks) ----------------
// Wave w owns neighbor rows w*16..w*16+15 (M=16 tile). Per-wave LDS region
// 4352 B: rbf [16][68] overlaid by H [16][136] (packed [row][col*8+nt], W2P
// K-permuted). LDS total 17408 B; __launch_bounds__(256,6) -> 6 blocks/CU
// (24 waves, 1.5x the old 16). b1/b2 folded into MFMA C-init. 3 barriers.
__global__ __launch_bounds__(256, 6) void k2_main(
    const float* __restrict__ rbf, const int* __restrict__ nl,
    const u16* __restrict__ initB,
    const u16* __restrict__ W1P, const u16* __restrict__ W2P,
    const float* __restrict__ b1, const float* __restrict__ b2,
    const float* __restrict__ nbrw,
    float* __restrict__ aggOut, float* __restrict__ attnO) {
    __shared__ alignas(16) char smem[17408];
    const int tid = threadIdx.x, wid = tid >> 6, lane = tid & 63;
    const int quad = lane >> 4, col = lane & 15;
    const int atom = blockIdx.x;           // 0..7999
    const int b = atom / NA;

    u16* wv = (u16*)smem + wid * 2176;     // per-wave region (4352 B = [16][136] u16)
    float* logitS = (float*)smem;          // [64]     bytes 0..255   (aliases wave0, post-barrier)
    float* aggS   = (float*)(smem + 256);  // [4][128] bytes 256..2303 (aliases wave0)

    // neighbor row offsets: 4 rows/thread (quad-broadcast loads)
    int rowoff[4];
#pragma unroll
    for (int r = 0; r < 4; ++r)
        rowoff[r] = (b * NA + nl[atom * MD + wid * 16 + quad * 4 + r]) * FD;

    // ---- per-wave rbf staging: rows wid*16..+15 -> wv [16][68] bf16 ----
    {
        const float* rsrc = rbf + (size_t)(atom * MD + wid * 16) * GD;
        for (int i = lane; i < 400; i += 64) {  // 800 floats as 400 pairs
            int e = 2 * i;
            int r = e / 50, g = e - r * 50;
            float2 v = *(const float2*)&rsrc[e];
            *(u32*)&wv[r * 68 + g] = pkbf(v.x, v.y);
        }
        for (int i = lane; i < 224; i += 64) {  // zero K-pad cols [50,64): 16x14
            int r = i / 14;
            wv[r * 68 + 50 + (i - r * 14)] = 0;
        }
    }

    // ---- layer 1: rbf @ W1 (M=16), C-init = b1 broadcast ----
    f32x4 acc[8];
#pragma unroll
    for (int nt = 0; nt < 8; ++nt) {
        float bb = b1[nt * 16 + col];
        f32x4 c = {bb, bb, bb, bb};
        acc[nt] = c;
    }
#pragma unroll
    for (int ks = 0; ks < 2; ++ks) {
        const int ka = ks * 32 + quad * 8;
        short8 a0 = *(const short8*)&wv[col * 68 + ka];
#pragma unroll
        for (int nt = 0; nt < 8; ++nt) {
            short8 bfr = *(const short8*)&W1P[((ks * 8 + nt) << 9) + (lane << 3)];
            acc[nt] = mfma16(a0, bfr, acc[nt]);
        }
    }

    // ---- H = tanh(acc) -> own-wave region PACKED [16 rows][col*8+nt] ----
#pragma unroll
    for (int r = 0; r < 4; ++r) {
        short8 h;
        u32* hp = (u32*)&h;
        hp[0] = pkbf(tanh_fast(acc[0][r]), tanh_fast(acc[1][r]));
        hp[1] = pkbf(tanh_fast(acc[2][r]), tanh_fast(acc[3][r]));
        hp[2] = pkbf(tanh_fast(acc[4][r]), tanh_fast(acc[5][r]));
        hp[3] = pkbf(tanh_fast(acc[6][r]), tanh_fast(acc[7][r]));
        *(short8*)&wv[(quad * 4 + r) * 136 + col * 8] = h;
    }

    // ---- layer 2: H @ W2 (K-permuted storage), C-init = b2 broadcast ----
    f32x4 acc2[8];
#pragma unroll
    for (int nt = 0; nt < 8; ++nt) {
        float bb = b2[nt * 16 + col];
        f32x4 c = {bb, bb, bb, bb};
        acc2[nt] = c;
    }
#pragma unroll
    for (int half = 0; half < 2; ++half)
#pragma unroll
        for (int ks = 0; ks < 2; ++ks) {
            const int ka = half * 64 + ks * 32 + quad * 8;
            short8 a0 = *(const short8*)&wv[col * 136 + ka];
#pragma unroll
            for (int nt = 0; nt < 8; ++nt) {
                short8 bfr = *(const short8*)&W2P[(((half * 2 + ks) * 8 + nt) << 9) + (lane << 3)];
                acc2[nt] = mfma16(a0, bfr, acc2[nt]);
            }
        }

    // ---- epilogue: conv (vector gather), logits ----
    float wv8[8];
#pragma unroll
    for (int nt = 0; nt < 8; ++nt) wv8[nt] = nbrw[nt * 16 + col];
    float part[4] = {0.f, 0.f, 0.f, 0.f};
#pragma unroll
    for (int r = 0; r < 4; ++r) {
        short8 g = *(const short8*)&initB[rowoff[r] + col * 8];
#pragma unroll
        for (int nt = 0; nt < 8; ++nt) {
            float nb = bf2f((u16)g[nt]);
            float cv = nb * acc2[nt][r];
            acc2[nt][r] = cv;  // conv stays in regs (fp32)
            part[r] += cv * wv8[nt];
        }
    }
#pragma unroll
    for (int d = 1; d < 16; d <<= 1)
#pragma unroll
        for (int r = 0; r < 4; ++r)
            part[r] += __shfl_xor(part[r], d, 64);

    __syncthreads();  // barrier 1: all waves' LDS reads done before aux aliases wave0 region
    if (col == 0) {
#pragma unroll
        for (int r = 0; r < 4; ++r)
            logitS[wid * 16 + quad * 4 + r] = part[r];
    }
    __syncthreads();  // barrier 2: logits visible

    // all-wave redundant softmax over the atom's 64 logits
    float attw[4];
    {
        float x = logitS[lane];
        float m = x;
#pragma unroll
        for (int d = 1; d < 64; d <<= 1) m = fmaxf(m, __shfl_xor(m, d, 64));
        float e = __expf(x - m);
        float s = e;
#pragma unroll
        for (int d = 1; d < 64; d <<= 1) s += __shfl_xor(s, d, 64);
        float a = e / s;
        if (wid == 0) attnO[(size_t)atom * MD + lane] = a;
#pragma unroll
        for (int r = 0; r < 4; ++r)
            attw[r] = __shfl(a, wid * 16 + quad * 4 + r, 64);
    }

    float aggp[8] = {0.f, 0.f, 0.f, 0.f, 0.f, 0.f, 0.f, 0.f};
#pragma unroll
    for (int r = 0; r < 4; ++r) {
        float a = attw[r];
#pragma unroll
        for (int nt = 0; nt < 8; ++nt) aggp[nt] += a * acc2[nt][r];
    }
#pragma unroll
    for (int d = 16; d < 64; d <<= 1)
#pragma unroll
        for (int nt = 0; nt < 8; ++nt) aggp[nt] += __shfl_xor(aggp[nt], d, 64);
    if (quad == 0) {
#pragma unroll
        for (int nt = 0; nt < 8; ++nt) aggS[wid * 128 + nt * 16 + col] = aggp[nt];
    }
    __syncthreads();  // barrier 3: partials visible
    if (tid < 128) {
        float v = aggS[tid] + aggS[128 + tid] + aggS[256 + tid] + aggS[384 + tid];
        aggOut[(size_t)atom * FD + tid] = v;  // agg scratch in d_out rows
    }
}

// ---------------- k3: out = tanh(agg@Wo1+bo1)@Wo2+bo2, IN PLACE on d_out rows ----------------
// 500 blocks x 64 threads, 16 rows/block. t1 PACKED [row][col*8+nt] with
// Wo2P K-permuted; bo1/bo2 folded into MFMA C-init. Single 1-wave barrier.
__global__ __launch_bounds__(64) void k3_out(
    float* __restrict__ outp, const u16* __restrict__ Wo1P,
    const u16* __restrict__ Wo2P, const float* __restrict__ bo1,
    const float* __restrict__ bo2) {
    __shared__ alignas(16) u16 sT[16 * 136];
    const int lane = threadIdx.x;
    const int quad = lane >> 4, col = lane & 15;
    const int row0 = blockIdx.x * 16;

    f32x4 acc[8];
#pragma unroll
    for (int nt = 0; nt < 8; ++nt) {
        float bb = bo1[nt * 16 + col];
        f32x4 c = {bb, bb, bb, bb};
        acc[nt] = c;
    }
#pragma unroll
    for (int half = 0; half < 2; ++half)
#pragma unroll
        for (int ks = 0; ks < 2; ++ks) {
            const int ka = half * 64 + ks * 32 + quad * 8;
            const float* src = &outp[(size_t)(row0 + col) * FD + ka];
            float4 v0 = *(const float4*)src;
            float4 v1 = *(const float4*)(src + 4);
            short8 a;
            u32* ap = (u32*)&a;
            ap[0] = pkbf(v0.x, v0.y);
            ap[1] = pkbf(v0.z, v0.w);
            ap[2] = pkbf(v1.x, v1.y);
            ap[3] = pkbf(v1.z, v1.w);
#pragma unroll
            for (int nt = 0; nt < 8; ++nt) {
                short8 bfr = *(const short8*)&Wo1P[(((half * 2 + ks) * 8 + nt) << 9) + (lane << 3)];
                acc[nt] = mfma16(a, bfr, acc[nt]);
            }
        }

#pragma unroll
    for (int r = 0; r < 4; ++r) {
        short8 h;
        u32* hp = (u32*)&h;
        hp[0] = pkbf(tanh_fast(acc[0][r]), tanh_fast(acc[1][r]));
        hp[1] = pkbf(tanh_fast(acc[2][r]), tanh_fast(acc[3][r]));
        hp[2] = pkbf(tanh_fast(acc[4][r]), tanh_fast(acc[5][r]));
        hp[3] = pkbf(tanh_fast(acc[6][r]), tanh_fast(acc[7][r]));
        *(short8*)&sT[(quad * 4 + r) * 136 + col * 8] = h;
    }
    __syncthreads();  // single-wave block: cheap; guarantees t1 write->read order

    f32x4 acc2[8];
#pragma unroll
    for (int nt = 0; nt < 8; ++nt) {
        float bb = bo2[nt * 16 + col];
        f32x4 c = {bb, bb, bb, bb};
        acc2[nt] = c;
    }
#pragma unroll
    for (int half = 0; half < 2; ++half)
#pragma unroll
        for (int ks = 0; ks < 2; ++ks) {
            const int ka = half * 64 + ks * 32 + quad * 8;
            short8 a0 = *(const short8*)&sT[col * 136 + ka];
#pragma unroll
            for (int nt = 0; nt < 8; ++nt) {
                short8 bfr = *(const short8*)&Wo2P[(((half * 2 + ks) * 8 + nt) << 9) + (lane << 3)];
                acc2[nt] = mfma16(a0, bfr, acc2[nt]);
            }
        }
#pragma unroll
    for (int nt = 0; nt < 8; ++nt)
#pragma unroll
        for (int r = 0; r < 4; ++r)
            outp[(size_t)(row0 + quad * 4 + r) * FD + nt * 16 + col] = acc2[nt][r];
}

extern "C" void kernel_launch(void* const* d_in, const int* in_sizes, int n_in,
                              void* d_out, int out_size, void* d_ws,
                              size_t ws_size, hipStream_t stream) {
    const float* feat = (const float*)d_in[0];
    const float* rbf  = (const float*)d_in[1];
    const int*   nl   = (const int*)d_in[2];
    const float* Wi   = (const float*)d_in[3];
    const float* W1   = (const float*)d_in[4];
    const float* b1   = (const float*)d_in[5];
    const float* W2   = (const float*)d_in[6];
    const float* b2   = (const float*)d_in[7];
    const float* nbrw = (const float*)d_in[8];
    const float* Wo1  = (const float*)d_in[9];
    const float* bo1  = (const float*)d_in[10];
    const float* Wo2  = (const float*)d_in[11];
    const float* bo2  = (const float*)d_in[12];

    float* outp  = (float*)d_out;               // [8000][128] (agg scratch, then final)
    float* attnp = outp + (size_t)TOTAL * FD;   // [8000][64]

    char* ws = (char*)d_ws;                     // total use: 2,195,456 B
    u16* initB = (u16*)ws;                      // 2,048,000 B
    u16* W1P   = (u16*)(ws + 2048000);          // 16,384 B
    u16* W2P   = (u16*)(ws + 2064384);          // 32,768 B
    u16* WiP   = (u16*)(ws + 2097152);          // 32,768 B
    u16* Wo1P  = (u16*)(ws + 2129920);          // 32,768 B
    u16* Wo2P  = (u16*)(ws + 2162688);          // 32,768 B

    hipLaunchKernelGGL(k0_prep, dim3(40), dim3(256), 0, stream,
                       W1, W2, Wi, Wo1, Wo2, W1P, W2P, WiP, Wo1P, Wo2P);
    hipLaunchKernelGGL(k1_init, dim3(500), dim3(64), 0, stream, feat, WiP, initB);
    hipLaunchKernelGGL(k2_main, dim3(8000), dim3(256), 0, stream,
                       rbf, nl, initB, W1P, W2P, b1, b2, nbrw, outp, attnp);
    hipLaunchKernelGGL(k3_out, dim3(500), dim3(64), 0, stream,
                       outp, Wo1P, Wo2P, bo1, bo2);
}